// Round 3
// baseline (137.077 us; speedup 1.0000x reference)
//
#include <hip/hip_runtime.h>
#include <hip/hip_fp16.h>

#define B_N 1024
#define D_K 128
#define C_N 100000
#define CT_PER_CHUNK 5                 // 32-c tiles per block
#define CCHUNK (CT_PER_CHUNK * 32)     // 160 c's per chunk
#define NCHUNK (C_N / CCHUNK)          // 625
#define BSPLIT 4                       // 4 blocks of 256 b's each
#define NBLK_MAIN (NCHUNK * BSPLIT)    // 2500
#define NREP 64
#define NPROXY_BLK (C_N / 4)           // 25000 prep blocks for proxies
#define EPSN 1e-12f

typedef _Float16 half8 __attribute__((ext_vector_type(8)));
typedef float floatx16 __attribute__((ext_vector_type(16)));

union U16 { uint4 u; half8 h; };

__device__ __forceinline__ unsigned int pack2h(float a, float b) {
    union { _Float16 h[2]; unsigned int u; } p;
    p.h[0] = (_Float16)a; p.h[1] = (_Float16)b;
    return p.u;
}

// ---------------------------------------------------------------------------
// Prep (merged): bx < 25000 -> normalize 4 proxy rows into fp16 A-frag order.
// bx >= 25000  -> x rows: ||x||^2, w, posd, xfrag (B-frag order, 2x baked in),
//                 zero negsumR (65536 floats == 256 blocks * 256 threads).
// Frag layout (32x32x16): element k of row r lives at
//   frag = (r>>5)*8 + (k>>4); slot = (r&31) | (((k>>3)&1)<<5); uint j=(k&7)>>1
// One wave per row: lane covers k = 2*lane, 2*lane+1 ->
//   ks = lane>>3, kh = (lane>>2)&1, jq = lane&3  (both halfs land in one uint)
// ---------------------------------------------------------------------------
__global__ __launch_bounds__(256) void prep_kernel(
    const float* __restrict__ xs, const int* __restrict__ ys,
    const float* __restrict__ proxies,
    unsigned int* __restrict__ pfrag, unsigned int* __restrict__ xfrag,
    float* __restrict__ w, float* __restrict__ posd,
    float* __restrict__ negsumR)
{
    int tid = threadIdx.x, wave = tid >> 6, lane = tid & 63;
    int bx = blockIdx.x;
    int ks = lane >> 3, kh = (lane >> 2) & 1, jq = lane & 3;

    if (bx < NPROXY_BLK) {
        int c = bx * 4 + wave;
        const float2 pv = ((const float2*)(proxies + (size_t)c * D_K))[lane];
        float ss = pv.x * pv.x + pv.y * pv.y;
        #pragma unroll
        for (int m = 1; m < 64; m <<= 1) ss += __shfl_xor(ss, m, 64);
        float sc = 1.0f / fmaxf(sqrtf(ss), EPSN);
        int idx = (((c >> 5) * 8 + ks) * 64 + ((c & 31) | (kh << 5))) * 4 + jq;
        pfrag[idx] = pack2h(pv.x * sc, pv.y * sc);
    } else {
        int bb = bx - NPROXY_BLK;              // 0..255
        negsumR[bb * 256 + tid] = 0.0f;        // 64 reps * 1024 = 65536 exactly

        int b = bb * 4 + wave;
        const float2 xv = ((const float2*)(xs + (size_t)b * D_K))[lane];
        float ss = xv.x * xv.x + xv.y * xv.y;
        #pragma unroll
        for (int m = 1; m < 64; m <<= 1) ss += __shfl_xor(ss, m, 64);
        float xsq = ss;

        // B-frag order, scaled by 2 so MFMA S = 2*x.p_hat directly
        int idx = (((b >> 5) * 8 + ks) * 64 + ((b & 31) | (kh << 5))) * 4 + jq;
        xfrag[idx] = pack2h(2.0f * xv.x, 2.0f * xv.y);

        // exact fp32 positive distance
        int y = ys[b];
        const float2 pv = ((const float2*)(proxies + (size_t)y * D_K))[lane];
        float dt = xv.x * pv.x + xv.y * pv.y;
        float pp = pv.x * pv.x + pv.y * pv.y;
        #pragma unroll
        for (int m = 1; m < 64; m <<= 1) {
            dt += __shfl_xor(dt, m, 64);
            pp += __shfl_xor(pp, m, 64);
        }
        if (lane == 0) {
            w[b] = __expf(-xsq - 1.0f);
            float nrm = fmaxf(sqrtf(pp), EPSN);
            posd[b] = xsq + 1.0f - 2.0f * (dt / nrm);
        }
    }
}

// ---------------------------------------------------------------------------
// Main: block = (c-chunk of 160, b-quarter of 256). Stage 40 KB of
// pre-normalized fp16 proxy fragments via global_load_lds (pure DMA, 40 x 1KB).
// Wave owns 64 b's (2 n-tiles); per 32-c tile: 8 ds_read_b128 + 2x8 MFMA
// (32x32x16 f16) + 32 exp. Per-b sums via in-register adds + one xor-32
// shuffle; one atomicAdd per b into striped negsum replica.
// ---------------------------------------------------------------------------
__global__ __launch_bounds__(256, 3) void main_kernel(
    const uint4* __restrict__ pfrag, const uint4* __restrict__ xfrag,
    const float* __restrict__ w, float* __restrict__ negsumR)
{
    __shared__ uint4 ldsP[CT_PER_CHUNK * 8 * 64];   // 40 frags * 1 KB = 40 KB

    int tid = threadIdx.x, wave = tid >> 6, lane = tid & 63;
    int bx = blockIdx.x;
    int cchunk = bx >> 2;          // adjacent blocks share chunk -> L2/L3 hits
    int bs = bx & 3;

    // ---- stage: 40 fragments, 10 DMA insts per wave ----
    {
        const uint4* src = pfrag + (size_t)cchunk * (CT_PER_CHUNK * 8 * 64);
        #pragma unroll
        for (int i = 0; i < 10; ++i) {
            int f = wave * 10 + i;
            __builtin_amdgcn_global_load_lds(
                (const __attribute__((address_space(1))) void*)(src + f * 64 + lane),
                (__attribute__((address_space(3))) void*)(ldsP + f * 64),
                16, 0, 0);
        }
    }

    // ---- per-wave x fragments: 2 n-tiles x 8 k-steps (64 VGPRs) ----
    int nt0 = bs * 8 + wave * 2;
    uint4 xf0[8], xf1[8];
    #pragma unroll
    for (int k = 0; k < 8; ++k) xf0[k] = xfrag[((nt0    ) * 8 + k) * 64 + lane];
    #pragma unroll
    for (int k = 0; k < 8; ++k) xf1[k] = xfrag[((nt0 + 1) * 8 + k) * 64 + lane];

    __syncthreads();   // drains the DMA (vmcnt) + barrier

    float s0 = 0.0f, s1 = 0.0f;

    #pragma unroll 1
    for (int ct = 0; ct < CT_PER_CHUNK; ++ct) {
        uint4 a[8];
        #pragma unroll
        for (int k = 0; k < 8; ++k)
            a[k] = ldsP[(ct * 8 + k) * 64 + lane];

        floatx16 acc0, acc1;
        #pragma unroll
        for (int i = 0; i < 16; ++i) { acc0[i] = 0.0f; acc1[i] = 0.0f; }

        #pragma unroll
        for (int k = 0; k < 8; ++k) {
            U16 ua, u0, u1;
            ua.u = a[k]; u0.u = xf0[k]; u1.u = xf1[k];
            acc0 = __builtin_amdgcn_mfma_f32_32x32x16_f16(ua.h, u0.h, acc0, 0, 0, 0);
            acc1 = __builtin_amdgcn_mfma_f32_32x32x16_f16(ua.h, u1.h, acc1, 0, 0, 0);
        }

        #pragma unroll
        for (int i = 0; i < 16; ++i) {
            s0 += __expf(acc0[i]);
            s1 += __expf(acc1[i]);
        }
    }

    // combine the two c-row halves (lanes l and l+32 hold the same b column)
    s0 += __shfl_xor(s0, 32, 64);
    s1 += __shfl_xor(s1, 32, 64);

    int rep = bx & (NREP - 1);
    if (lane < 32) {
        int b0 = bs * 256 + wave * 64 + lane;       // n-tile 0
        int b1 = b0 + 32;                           // n-tile 1
        atomicAdd(&negsumR[rep * B_N + b0], s0 * w[b0]);
        atomicAdd(&negsumR[rep * B_N + b1], s1 * w[b1]);
    }
}

// ---------------------------------------------------------------------------
// Finalize: loss = mean_b [ log(sum_r negsumR[r][b] - exp(-posd[b])) + posd[b] ]
// ---------------------------------------------------------------------------
__global__ __launch_bounds__(1024) void final_kernel(
    const float* __restrict__ negsumR, const float* __restrict__ posd,
    float* __restrict__ out)
{
    __shared__ float red[1024];
    int t = threadIdx.x;
    float ns = 0.0f;
    #pragma unroll 4
    for (int r = 0; r < NREP; ++r) ns += negsumR[r * B_N + t];
    float pd = posd[t];
    red[t] = logf(ns - __expf(-pd)) + pd;
    __syncthreads();
    #pragma unroll
    for (int s = 512; s > 0; s >>= 1) {
        if (t < s) red[t] += red[t + s];
        __syncthreads();
    }
    if (t == 0) out[0] = red[0] * (1.0f / 1024.0f);
}

extern "C" void kernel_launch(void* const* d_in, const int* in_sizes, int n_in,
                              void* d_out, int out_size, void* d_ws, size_t ws_size,
                              hipStream_t stream)
{
    const float* xs      = (const float*)d_in[0];
    const int*   ys      = (const int*)d_in[1];
    const float* proxies = (const float*)d_in[2];

    char* ws = (char*)d_ws;
    // pfrag: 100000*128 fp16 = 25,600,000 B
    unsigned int* pfrag   = (unsigned int*)ws;
    unsigned int* xfrag   = (unsigned int*)(ws + 25600000);            // 256 KB
    float*        w       = (float*)(ws + 25600000 + 262144);          // 4 KB
    float*        posd    = (float*)(ws + 25600000 + 262144 + 4096);   // 4 KB
    float*        negsumR = (float*)(ws + 25600000 + 262144 + 8192);   // 256 KB

    prep_kernel<<<NPROXY_BLK + 256, 256, 0, stream>>>(
        xs, ys, proxies, pfrag, xfrag, w, posd, negsumR);
    main_kernel<<<NBLK_MAIN, 256, 0, stream>>>(
        (const uint4*)pfrag, (const uint4*)xfrag, w, negsumR);
    final_kernel<<<1, 1024, 0, stream>>>(negsumR, posd, (float*)d_out);
}

// Round 4
// 130.811 us; speedup vs baseline: 1.0479x; 1.0479x over previous
//
#include <hip/hip_runtime.h>
#include <hip/hip_fp16.h>

#define B_N 1024
#define D_K 128
#define C_N 100000
#define CT_PER_CHUNK 5                 // 32-c tiles per main block
#define CCHUNK (CT_PER_CHUNK * 32)     // 160
#define NCHUNK (C_N / CCHUNK)          // 625
#define BSPLIT 2                       // 2 b-halves of 512
#define NBLK_MAIN (NCHUNK * BSPLIT)    // 1250
#define NREP 64
#define NPROXY_BLK (C_N / 32)          // 3125 transpose blocks (one 32-c tile each)
#define EPSN 1e-12f

typedef _Float16 half8 __attribute__((ext_vector_type(8)));
typedef float floatx16 __attribute__((ext_vector_type(16)));

union U16 { uint4 u; half8 h; };

__device__ __forceinline__ unsigned int pack2h(float a, float b) {
    union { _Float16 h[2]; unsigned int u; } p;
    p.h[0] = (_Float16)a; p.h[1] = (_Float16)b;
    return p.u;
}

// ---------------------------------------------------------------------------
// Prep. bx < 3125: one 32-c proxy tile -> normalize -> fp16 A-frag order,
// fully coalesced reads (float4) and 128-B-segment writes (2 x uint4/lane).
// Frag layout (32x32x16 A): tile t, k-step s=k>>4 -> frag t*8+s (64 uint4);
// slot = (c&31) | ((k&15)>>3)<<5; halves j = k&7. Lane (r=tid>>3, L=tid&7)
// covers k in [16L,16L+16) of row c0+r == frag L, slots r and r+32. Exact.
// bx >= 3125: x rows -> ||x||^2, w, posd, xfrag (B-frag order, 2x baked),
// zero negsumR.
// ---------------------------------------------------------------------------
__global__ __launch_bounds__(256) void prep_kernel(
    const float* __restrict__ xs, const int* __restrict__ ys,
    const float* __restrict__ proxies,
    uint4* __restrict__ pfrag, unsigned int* __restrict__ xfrag,
    float* __restrict__ w, float* __restrict__ posd,
    float* __restrict__ negsumR)
{
    int tid = threadIdx.x, bx = blockIdx.x;

    if (bx < NPROXY_BLK) {
        int L = tid & 7;          // k-segment: k in [16L, 16L+16)
        int r = tid >> 3;         // row within tile: 0..31
        int c = bx * 32 + r;
        const float4* src = (const float4*)(proxies + (size_t)c * D_K + L * 16);
        float4 v0 = src[0], v1 = src[1], v2 = src[2], v3 = src[3];
        float ss = v0.x*v0.x + v0.y*v0.y + v0.z*v0.z + v0.w*v0.w
                 + v1.x*v1.x + v1.y*v1.y + v1.z*v1.z + v1.w*v1.w
                 + v2.x*v2.x + v2.y*v2.y + v2.z*v2.z + v2.w*v2.w
                 + v3.x*v3.x + v3.y*v3.y + v3.z*v3.z + v3.w*v3.w;
        ss += __shfl_xor(ss, 1, 64);
        ss += __shfl_xor(ss, 2, 64);
        ss += __shfl_xor(ss, 4, 64);
        float sc = 1.0f / fmaxf(sqrtf(ss), EPSN);

        union { _Float16 h[8]; uint4 u; } pa, pb;
        pa.h[0]=(_Float16)(v0.x*sc); pa.h[1]=(_Float16)(v0.y*sc);
        pa.h[2]=(_Float16)(v0.z*sc); pa.h[3]=(_Float16)(v0.w*sc);
        pa.h[4]=(_Float16)(v1.x*sc); pa.h[5]=(_Float16)(v1.y*sc);
        pa.h[6]=(_Float16)(v1.z*sc); pa.h[7]=(_Float16)(v1.w*sc);
        pb.h[0]=(_Float16)(v2.x*sc); pb.h[1]=(_Float16)(v2.y*sc);
        pb.h[2]=(_Float16)(v2.z*sc); pb.h[3]=(_Float16)(v2.w*sc);
        pb.h[4]=(_Float16)(v3.x*sc); pb.h[5]=(_Float16)(v3.y*sc);
        pb.h[6]=(_Float16)(v3.z*sc); pb.h[7]=(_Float16)(v3.w*sc);

        uint4* dst = pfrag + (size_t)bx * 512;   // tile = 8 frags * 64 uint4
        dst[L * 64 + r]      = pa.u;
        dst[L * 64 + 32 + r] = pb.u;
    } else {
        int bb = bx - NPROXY_BLK;              // 0..255
        negsumR[bb * 256 + tid] = 0.0f;        // 64 reps * 1024 floats exactly

        int wave = tid >> 6, lane = tid & 63;
        int b = bb * 4 + wave;
        const float2 xv = ((const float2*)(xs + (size_t)b * D_K))[lane];
        float ss = xv.x * xv.x + xv.y * xv.y;
        #pragma unroll
        for (int m = 1; m < 64; m <<= 1) ss += __shfl_xor(ss, m, 64);
        float xsq = ss;

        // B-frag order (32x32x16), scaled by 2 so MFMA S = 2*x.p_hat
        int ks = lane >> 3, kh = (lane >> 2) & 1, jq = lane & 3;
        int idx = (((b >> 5) * 8 + ks) * 64 + ((b & 31) | (kh << 5))) * 4 + jq;
        xfrag[idx] = pack2h(2.0f * xv.x, 2.0f * xv.y);

        // exact fp32 positive distance
        int y = ys[b];
        const float2 pv = ((const float2*)(proxies + (size_t)y * D_K))[lane];
        float dt = xv.x * pv.x + xv.y * pv.y;
        float pp = pv.x * pv.x + pv.y * pv.y;
        #pragma unroll
        for (int m = 1; m < 64; m <<= 1) {
            dt += __shfl_xor(dt, m, 64);
            pp += __shfl_xor(pp, m, 64);
        }
        if (lane == 0) {
            w[b] = __expf(-xsq - 1.0f);
            float nrm = fmaxf(sqrtf(pp), EPSN);
            posd[b] = xsq + 1.0f - 2.0f * (dt / nrm);
        }
    }
}

// ---------------------------------------------------------------------------
// Compute 5 c-tiles x 2 n-tiles for one wave: 80 MFMA (32x32x16), exp-sum
// with 2 partial accumulators per tile to break the dependent add chain.
// ---------------------------------------------------------------------------
__device__ __forceinline__ void compute_pair(
    const uint4* ldsP, int lane,
    const uint4 xfA[8], const uint4 xfB[8],
    float& outA, float& outB)
{
    float sA0 = 0.f, sA1 = 0.f, sB0 = 0.f, sB1 = 0.f;
    #pragma unroll 1
    for (int ct = 0; ct < CT_PER_CHUNK; ++ct) {
        uint4 a[8];
        #pragma unroll
        for (int k = 0; k < 8; ++k)
            a[k] = ldsP[(ct * 8 + k) * 64 + lane];

        floatx16 accA, accB;
        #pragma unroll
        for (int i = 0; i < 16; ++i) { accA[i] = 0.0f; accB[i] = 0.0f; }

        #pragma unroll
        for (int k = 0; k < 8; ++k) {
            U16 ua, u0, u1;
            ua.u = a[k]; u0.u = xfA[k]; u1.u = xfB[k];
            accA = __builtin_amdgcn_mfma_f32_32x32x16_f16(ua.h, u0.h, accA, 0, 0, 0);
            accB = __builtin_amdgcn_mfma_f32_32x32x16_f16(ua.h, u1.h, accB, 0, 0, 0);
        }

        #pragma unroll
        for (int i = 0; i < 16; i += 2) {
            sA0 += __expf(accA[i]);     sA1 += __expf(accA[i + 1]);
            sB0 += __expf(accB[i]);     sB1 += __expf(accB[i + 1]);
        }
    }
    outA = sA0 + sA1;
    outB = sB0 + sB1;
}

// ---------------------------------------------------------------------------
// Main: block = (c-chunk of 160, b-half of 512). Stage 40 KB pre-normalized
// fp16 proxy frags via pure global_load_lds DMA (each chunk staged only
// BSPLIT=2 times -> 51 MB total DMA, half of round 3). Wave owns 128 b's
// (4 n-tiles), processed as two pairs; second pair's x-frags load from
// L2-hot xfrag between the compute halves to overlap latency.
// ---------------------------------------------------------------------------
__global__ __launch_bounds__(256, 3) void main_kernel(
    const uint4* __restrict__ pfrag, const uint4* __restrict__ xfrag,
    const float* __restrict__ w, float* __restrict__ negsumR)
{
    __shared__ uint4 ldsP[CT_PER_CHUNK * 8 * 64];   // 40 KB

    int tid = threadIdx.x, wave = tid >> 6, lane = tid & 63;
    int bx = blockIdx.x;
    int cchunk = bx >> 1;          // adjacent blocks share chunk -> L3 hits
    int bs = bx & 1;

    // ---- stage: 40 frags, 10 DMA insts per wave ----
    {
        const uint4* src = pfrag + (size_t)cchunk * (CT_PER_CHUNK * 8 * 64);
        #pragma unroll
        for (int i = 0; i < 10; ++i) {
            int f = wave * 10 + i;
            __builtin_amdgcn_global_load_lds(
                (const __attribute__((address_space(1))) void*)(src + f * 64 + lane),
                (__attribute__((address_space(3))) void*)(ldsP + f * 64),
                16, 0, 0);
        }
    }

    int nt0 = bs * 16 + wave * 4;     // first of this wave's 4 n-tiles
    uint4 xfA[8], xfB[8];
    #pragma unroll
    for (int k = 0; k < 8; ++k) xfA[k] = xfrag[((nt0    ) * 8 + k) * 64 + lane];
    #pragma unroll
    for (int k = 0; k < 8; ++k) xfB[k] = xfrag[((nt0 + 1) * 8 + k) * 64 + lane];

    __syncthreads();   // drains DMA + barrier

    int rep = bx & (NREP - 1);
    float* nsr = negsumR + (size_t)rep * B_N;

    float s0, s1;
    compute_pair(ldsP, lane, xfA, xfB, s0, s1);

    // overlap: fetch second pair's x-frags before the epilogue of pair 1
    #pragma unroll
    for (int k = 0; k < 8; ++k) xfA[k] = xfrag[((nt0 + 2) * 8 + k) * 64 + lane];
    #pragma unroll
    for (int k = 0; k < 8; ++k) xfB[k] = xfrag[((nt0 + 3) * 8 + k) * 64 + lane];

    s0 += __shfl_xor(s0, 32, 64);     // combine the two c-row halves
    s1 += __shfl_xor(s1, 32, 64);
    if (lane < 32) {
        int b0 = (nt0    ) * 32 + lane;
        int b1 = (nt0 + 1) * 32 + lane;
        atomicAdd(&nsr[b0], s0 * w[b0]);
        atomicAdd(&nsr[b1], s1 * w[b1]);
    }

    float s2, s3;
    compute_pair(ldsP, lane, xfA, xfB, s2, s3);
    s2 += __shfl_xor(s2, 32, 64);
    s3 += __shfl_xor(s3, 32, 64);
    if (lane < 32) {
        int b2 = (nt0 + 2) * 32 + lane;
        int b3 = (nt0 + 3) * 32 + lane;
        atomicAdd(&nsr[b2], s2 * w[b2]);
        atomicAdd(&nsr[b3], s3 * w[b3]);
    }
}

// ---------------------------------------------------------------------------
// Finalize: loss = mean_b [ log(sum_r negsumR[r][b] - exp(-posd[b])) + posd[b] ]
// ---------------------------------------------------------------------------
__global__ __launch_bounds__(1024) void final_kernel(
    const float* __restrict__ negsumR, const float* __restrict__ posd,
    float* __restrict__ out)
{
    __shared__ float red[1024];
    int t = threadIdx.x;
    float ns = 0.0f;
    #pragma unroll 4
    for (int r = 0; r < NREP; ++r) ns += negsumR[r * B_N + t];
    float pd = posd[t];
    red[t] = logf(ns - __expf(-pd)) + pd;
    __syncthreads();
    #pragma unroll
    for (int s = 512; s > 0; s >>= 1) {
        if (t < s) red[t] += red[t + s];
        __syncthreads();
    }
    if (t == 0) out[0] = red[0] * (1.0f / 1024.0f);
}

extern "C" void kernel_launch(void* const* d_in, const int* in_sizes, int n_in,
                              void* d_out, int out_size, void* d_ws, size_t ws_size,
                              hipStream_t stream)
{
    const float* xs      = (const float*)d_in[0];
    const int*   ys      = (const int*)d_in[1];
    const float* proxies = (const float*)d_in[2];

    char* ws = (char*)d_ws;
    // pfrag: 100000*128 fp16 = 25,600,000 B
    uint4*        pfrag   = (uint4*)ws;
    unsigned int* xfrag   = (unsigned int*)(ws + 25600000);            // 256 KB
    float*        w       = (float*)(ws + 25600000 + 262144);          // 4 KB
    float*        posd    = (float*)(ws + 25600000 + 262144 + 4096);   // 4 KB
    float*        negsumR = (float*)(ws + 25600000 + 262144 + 8192);   // 256 KB

    prep_kernel<<<NPROXY_BLK + 256, 256, 0, stream>>>(
        xs, ys, proxies, pfrag, xfrag, w, posd, negsumR);
    main_kernel<<<NBLK_MAIN, 256, 0, stream>>>(
        pfrag, (const uint4*)xfrag, w, negsumR);
    final_kernel<<<1, 1024, 0, stream>>>(negsumR, posd, (float*)d_out);
}

// Round 6
// 125.263 us; speedup vs baseline: 1.0943x; 1.0443x over previous
//
#include <hip/hip_runtime.h>
#include <hip/hip_fp16.h>

#define B_N 1024
#define D_K 128
#define C_N 100000
#define CT_PER_CHUNK 5                 // 32-c tiles per chunk
#define CCHUNK (CT_PER_CHUNK * 32)     // 160 c per chunk
#define NCHUNK (C_N / CCHUNK)          // 625
#define BSPLIT 2                       // 2 b-halves of 512
#define NBLK_MAIN (NCHUNK * BSPLIT)    // 1250
#define NREP 64
#define K2LOG2E 2.8853900817779268f    // 2*log2(e), baked into xfrag
#define EPSN 1e-12f

typedef _Float16 half8 __attribute__((ext_vector_type(8)));
typedef float floatx16 __attribute__((ext_vector_type(16)));

union U16 { uint4 u; half8 h; };

// native v_exp_f32: computes 2^x
#define EXP2F(x) __builtin_amdgcn_exp2f(x)

__device__ __forceinline__ unsigned int pack2h(float a, float b) {
    union { _Float16 h[2]; unsigned int u; } p;
    p.h[0] = (_Float16)a; p.h[1] = (_Float16)b;
    return p.u;
}

// ---------------------------------------------------------------------------
// Prep (x only, tiny): per-row ||x||^2, w[b]=exp(-||x||^2-1), xfrag in
// 32x32x16 B-frag order holding (2*log2e)*x as fp16 (so main's exp is a bare
// v_exp_f32), exact fp32 positive distance posd[b], zero negsumR.
// 256 blocks; one wave per row b.
// ---------------------------------------------------------------------------
__global__ __launch_bounds__(256) void prep_kernel(
    const float* __restrict__ xs, const int* __restrict__ ys,
    const float* __restrict__ proxies,
    unsigned int* __restrict__ xfrag, float* __restrict__ w,
    float* __restrict__ posd, float* __restrict__ negsumR)
{
    int tid = threadIdx.x, bb = blockIdx.x;
    negsumR[bb * 256 + tid] = 0.0f;        // 64 reps * 1024 floats exactly

    int wave = tid >> 6, lane = tid & 63;
    int b = bb * 4 + wave;
    const float2 xv = ((const float2*)(xs + (size_t)b * D_K))[lane];
    float ss = xv.x * xv.x + xv.y * xv.y;
    #pragma unroll
    for (int m = 1; m < 64; m <<= 1) ss += __shfl_xor(ss, m, 64);
    float xsq = ss;

    // B-frag order (32x32x16): lane covers k = 2*lane, 2*lane+1
    int ks = lane >> 3, kh = (lane >> 2) & 1, jq = lane & 3;
    int idx = (((b >> 5) * 8 + ks) * 64 + ((b & 31) | (kh << 5))) * 4 + jq;
    xfrag[idx] = pack2h(K2LOG2E * xv.x, K2LOG2E * xv.y);

    // exact fp32 positive distance
    int y = ys[b];
    const float2 pv = ((const float2*)(proxies + (size_t)y * D_K))[lane];
    float dt = xv.x * pv.x + xv.y * pv.y;
    float pp = pv.x * pv.x + pv.y * pv.y;
    #pragma unroll
    for (int m = 1; m < 64; m <<= 1) {
        dt += __shfl_xor(dt, m, 64);
        pp += __shfl_xor(pp, m, 64);
    }
    if (lane == 0) {
        w[b] = __expf(-xsq - 1.0f);
        float nrm = fmaxf(sqrtf(pp), EPSN);
        posd[b] = xsq + 1.0f - 2.0f * (dt / nrm);
    }
}

// ---------------------------------------------------------------------------
// 5 c-tiles x 2 n-tiles for one wave: 80 MFMA (32x32x16 f16) + bare-exp2
// epilogue with 4 partial accumulators (no dependent add chain).
// ---------------------------------------------------------------------------
__device__ __forceinline__ void compute_pair(
    const uint4* ldsP, int lane,
    const uint4 xfA[8], const uint4 xfB[8],
    float& outA, float& outB)
{
    float sA0 = 0.f, sA1 = 0.f, sB0 = 0.f, sB1 = 0.f;
    #pragma unroll 1
    for (int ct = 0; ct < CT_PER_CHUNK; ++ct) {
        uint4 a[8];
        #pragma unroll
        for (int k = 0; k < 8; ++k)
            a[k] = ldsP[(ct * 8 + k) * 64 + lane];

        floatx16 accA, accB;
        #pragma unroll
        for (int i = 0; i < 16; ++i) { accA[i] = 0.0f; accB[i] = 0.0f; }

        #pragma unroll
        for (int k = 0; k < 8; ++k) {
            U16 ua, u0, u1;
            ua.u = a[k]; u0.u = xfA[k]; u1.u = xfB[k];
            accA = __builtin_amdgcn_mfma_f32_32x32x16_f16(ua.h, u0.h, accA, 0, 0, 0);
            accB = __builtin_amdgcn_mfma_f32_32x32x16_f16(ua.h, u1.h, accB, 0, 0, 0);
        }

        // acc = (2*log2e) * x . p_hat  ->  exp2(acc) = exp(2 x . p_hat)
        #pragma unroll
        for (int i = 0; i < 16; i += 2) {
            sA0 += EXP2F(accA[i]);     sA1 += EXP2F(accA[i + 1]);
            sB0 += EXP2F(accB[i]);     sB1 += EXP2F(accB[i + 1]);
        }
    }
    outA = sA0 + sA1;
    outB = sB0 + sB1;
}

// ---------------------------------------------------------------------------
// Main (single pass over proxies, no pfrag round-trip): block = (chunk of
// 160 c, b-half of 512). Stage: read proxies fp32 coalesced (8 lanes/row,
// 64 B/lane), normalize via 8-lane shuffle, pack fp16 into LDS in A-frag
// order (same layout that verified absmax 0.0 in rounds 3-4). Compute:
// wave owns 128 b (4 n-tiles as 2 pairs), second pair's x-frags prefetched
// between halves; one atomicAdd per b into striped negsum replica.
// ---------------------------------------------------------------------------
__global__ __launch_bounds__(256, 3) void main_kernel(
    const float* __restrict__ proxies,
    const uint4* __restrict__ xfrag,
    const float* __restrict__ w, float* __restrict__ negsumR)
{
    __shared__ uint4 ldsP[CT_PER_CHUNK * 8 * 64];   // 2560 uint4 = 40 KB

    int tid = threadIdx.x, wave = tid >> 6, lane = tid & 63;
    int bx = blockIdx.x;
    int c0 = (bx >> 1) * CCHUNK;   // adjacent blocks share chunk -> L3 hit
    int bs = bx & 1;

    // ---- stage + normalize: L = k-segment [16L,16L+16), r = row in tile ----
    {
        int L = tid & 7;
        int r = tid >> 3;          // 0..31
        #pragma unroll 1
        for (int p = 0; p < CT_PER_CHUNK; ++p) {
            int c = c0 + p * 32 + r;
            const float4* src = (const float4*)(proxies + (size_t)c * D_K + L * 16);
            float4 v0 = src[0], v1 = src[1], v2 = src[2], v3 = src[3];
            float ss = v0.x*v0.x + v0.y*v0.y + v0.z*v0.z + v0.w*v0.w
                     + v1.x*v1.x + v1.y*v1.y + v1.z*v1.z + v1.w*v1.w
                     + v2.x*v2.x + v2.y*v2.y + v2.z*v2.z + v2.w*v2.w
                     + v3.x*v3.x + v3.y*v3.y + v3.z*v3.z + v3.w*v3.w;
            ss += __shfl_xor(ss, 1, 64);
            ss += __shfl_xor(ss, 2, 64);
            ss += __shfl_xor(ss, 4, 64);
            float sc = 1.0f / fmaxf(sqrtf(ss), EPSN);

            union { _Float16 h[8]; uint4 u; } pa, pb;
            pa.h[0]=(_Float16)(v0.x*sc); pa.h[1]=(_Float16)(v0.y*sc);
            pa.h[2]=(_Float16)(v0.z*sc); pa.h[3]=(_Float16)(v0.w*sc);
            pa.h[4]=(_Float16)(v1.x*sc); pa.h[5]=(_Float16)(v1.y*sc);
            pa.h[6]=(_Float16)(v1.z*sc); pa.h[7]=(_Float16)(v1.w*sc);
            pb.h[0]=(_Float16)(v2.x*sc); pb.h[1]=(_Float16)(v2.y*sc);
            pb.h[2]=(_Float16)(v2.z*sc); pb.h[3]=(_Float16)(v2.w*sc);
            pb.h[4]=(_Float16)(v3.x*sc); pb.h[5]=(_Float16)(v3.y*sc);
            pb.h[6]=(_Float16)(v3.z*sc); pb.h[7]=(_Float16)(v3.w*sc);

            // tile p, frag L, slots r and r+32 (A-frag order)
            ldsP[p * 512 + L * 64 + r]      = pa.u;
            ldsP[p * 512 + L * 64 + 32 + r] = pb.u;
        }
    }

    // ---- first pair's x-frags while stage writes drain ----
    int nt0 = bs * 16 + wave * 4;
    uint4 xfA[8], xfB[8];
    #pragma unroll
    for (int k = 0; k < 8; ++k) xfA[k] = xfrag[((nt0    ) * 8 + k) * 64 + lane];
    #pragma unroll
    for (int k = 0; k < 8; ++k) xfB[k] = xfrag[((nt0 + 1) * 8 + k) * 64 + lane];

    __syncthreads();

    int rep = bx & (NREP - 1);
    float* nsr = negsumR + (size_t)rep * B_N;

    float s0, s1;
    compute_pair(ldsP, lane, xfA, xfB, s0, s1);

    // prefetch second pair's x-frags before the epilogue of pair 1
    #pragma unroll
    for (int k = 0; k < 8; ++k) xfA[k] = xfrag[((nt0 + 2) * 8 + k) * 64 + lane];
    #pragma unroll
    for (int k = 0; k < 8; ++k) xfB[k] = xfrag[((nt0 + 3) * 8 + k) * 64 + lane];

    s0 += __shfl_xor(s0, 32, 64);     // combine the two c-row halves
    s1 += __shfl_xor(s1, 32, 64);
    if (lane < 32) {
        int b0 = (nt0    ) * 32 + lane;
        int b1 = (nt0 + 1) * 32 + lane;
        atomicAdd(&nsr[b0], s0 * w[b0]);
        atomicAdd(&nsr[b1], s1 * w[b1]);
    }

    float s2, s3;
    compute_pair(ldsP, lane, xfA, xfB, s2, s3);
    s2 += __shfl_xor(s2, 32, 64);
    s3 += __shfl_xor(s3, 32, 64);
    if (lane < 32) {
        int b2 = (nt0 + 2) * 32 + lane;
        int b3 = (nt0 + 3) * 32 + lane;
        atomicAdd(&nsr[b2], s2 * w[b2]);
        atomicAdd(&nsr[b3], s3 * w[b3]);
    }
}

// ---------------------------------------------------------------------------
// Finalize: loss = mean_b [ log(sum_r negsumR[r][b] - exp(-posd[b])) + posd[b] ]
// ---------------------------------------------------------------------------
__global__ __launch_bounds__(1024) void final_kernel(
    const float* __restrict__ negsumR, const float* __restrict__ posd,
    float* __restrict__ out)
{
    __shared__ float red[1024];
    int t = threadIdx.x;
    float ns = 0.0f;
    #pragma unroll 4
    for (int r = 0; r < NREP; ++r) ns += negsumR[r * B_N + t];
    float pd = posd[t];
    red[t] = logf(ns - __expf(-pd)) + pd;
    __syncthreads();
    #pragma unroll
    for (int s = 512; s > 0; s >>= 1) {
        if (t < s) red[t] += red[t + s];
        __syncthreads();
    }
    if (t == 0) out[0] = red[0] * (1.0f / 1024.0f);
}

extern "C" void kernel_launch(void* const* d_in, const int* in_sizes, int n_in,
                              void* d_out, int out_size, void* d_ws, size_t ws_size,
                              hipStream_t stream)
{
    const float* xs      = (const float*)d_in[0];
    const int*   ys      = (const int*)d_in[1];
    const float* proxies = (const float*)d_in[2];

    char* ws = (char*)d_ws;
    unsigned int* xfrag   = (unsigned int*)ws;                 // 256 KB
    float*        w       = (float*)(ws + 262144);             // 4 KB
    float*        posd    = (float*)(ws + 262144 + 4096);      // 4 KB
    float*        negsumR = (float*)(ws + 262144 + 8192);      // 256 KB (64 reps)

    prep_kernel<<<256, 256, 0, stream>>>(xs, ys, proxies, xfrag, w, posd, negsumR);
    main_kernel<<<NBLK_MAIN, 256, 0, stream>>>(proxies, (const uint4*)xfrag, w, negsumR);
    final_kernel<<<1, 1024, 0, stream>>>(negsumR, posd, (float*)d_out);
}

// Round 7
// 124.241 us; speedup vs baseline: 1.1033x; 1.0082x over previous
//
#include <hip/hip_runtime.h>
#include <hip/hip_fp16.h>

#define B_N 1024
#define D_K 128
#define C_N 100000
#define NTILE 3125                     // 32-c tiles
#define NPAIR 512                      // block pairs; pair p owns tiles p, p+512, ...
#define NBLK_MAIN (NPAIR * 2)          // 1024 persistent blocks (b-half each)
#define NREP 64
#define K2LOG2E 2.8853900817779268f    // 2*log2(e), baked into xfrag
#define EPSN 1e-12f

typedef _Float16 half8 __attribute__((ext_vector_type(8)));
typedef float floatx16 __attribute__((ext_vector_type(16)));

union U16 { uint4 u; half8 h; };

#define EXP2F(x) __builtin_amdgcn_exp2f(x)   // bare v_exp_f32: 2^x

__device__ __forceinline__ unsigned int pack2h(float a, float b) {
    union { _Float16 h[2]; unsigned int u; } p;
    p.h[0] = (_Float16)a; p.h[1] = (_Float16)b;
    return p.u;
}

// ---------------------------------------------------------------------------
// Prep (x only): ||x||^2, w[b]=exp(-||x||^2-1), xfrag in 32x32x16 B-frag
// order holding (2*log2e)*x fp16, exact fp32 posd[b], zero negsumR.
// ---------------------------------------------------------------------------
__global__ __launch_bounds__(256) void prep_kernel(
    const float* __restrict__ xs, const int* __restrict__ ys,
    const float* __restrict__ proxies,
    unsigned int* __restrict__ xfrag, float* __restrict__ w,
    float* __restrict__ posd, float* __restrict__ negsumR)
{
    int tid = threadIdx.x, bb = blockIdx.x;
    negsumR[bb * 256 + tid] = 0.0f;        // 64 reps * 1024 floats exactly

    int wave = tid >> 6, lane = tid & 63;
    int b = bb * 4 + wave;
    const float2 xv = ((const float2*)(xs + (size_t)b * D_K))[lane];
    float ss = xv.x * xv.x + xv.y * xv.y;
    #pragma unroll
    for (int m = 1; m < 64; m <<= 1) ss += __shfl_xor(ss, m, 64);
    float xsq = ss;

    int ks = lane >> 3, kh = (lane >> 2) & 1, jq = lane & 3;
    int idx = (((b >> 5) * 8 + ks) * 64 + ((b & 31) | (kh << 5))) * 4 + jq;
    xfrag[idx] = pack2h(K2LOG2E * xv.x, K2LOG2E * xv.y);

    int y = ys[b];
    const float2 pv = ((const float2*)(proxies + (size_t)y * D_K))[lane];
    float dt = xv.x * pv.x + xv.y * pv.y;
    float pp = pv.x * pv.x + pv.y * pv.y;
    #pragma unroll
    for (int m = 1; m < 64; m <<= 1) {
        dt += __shfl_xor(dt, m, 64);
        pp += __shfl_xor(pp, m, 64);
    }
    if (lane == 0) {
        w[b] = __expf(-xsq - 1.0f);
        float nrm = fmaxf(sqrtf(pp), EPSN);
        posd[b] = xsq + 1.0f - 2.0f * (dt / nrm);
    }
}

// ---------------------------------------------------------------------------
// Normalize one 16-float row segment and write it into an LDS tile buffer
// in XOR-swizzled A-frag order. Row r (0..31), segment L (0..7, k=16L..16L+15).
// slot = r ^ L breaks the 8-way write bank conflict (octet r%8=const hits
// 8 disjoint bank quads); read side compensates with lane ^ k.
// ---------------------------------------------------------------------------
__device__ __forceinline__ void stage_write(
    uint4* dst, int L, int r, float4 v0, float4 v1, float4 v2, float4 v3)
{
    float ss = v0.x*v0.x + v0.y*v0.y + v0.z*v0.z + v0.w*v0.w
             + v1.x*v1.x + v1.y*v1.y + v1.z*v1.z + v1.w*v1.w
             + v2.x*v2.x + v2.y*v2.y + v2.z*v2.z + v2.w*v2.w
             + v3.x*v3.x + v3.y*v3.y + v3.z*v3.z + v3.w*v3.w;
    ss += __shfl_xor(ss, 1, 64);
    ss += __shfl_xor(ss, 2, 64);
    ss += __shfl_xor(ss, 4, 64);
    float sc = 1.0f / fmaxf(sqrtf(ss), EPSN);

    union { _Float16 h[8]; uint4 u; } pa, pb;
    pa.h[0]=(_Float16)(v0.x*sc); pa.h[1]=(_Float16)(v0.y*sc);
    pa.h[2]=(_Float16)(v0.z*sc); pa.h[3]=(_Float16)(v0.w*sc);
    pa.h[4]=(_Float16)(v1.x*sc); pa.h[5]=(_Float16)(v1.y*sc);
    pa.h[6]=(_Float16)(v1.z*sc); pa.h[7]=(_Float16)(v1.w*sc);
    pb.h[0]=(_Float16)(v2.x*sc); pb.h[1]=(_Float16)(v2.y*sc);
    pb.h[2]=(_Float16)(v2.z*sc); pb.h[3]=(_Float16)(v2.w*sc);
    pb.h[4]=(_Float16)(v3.x*sc); pb.h[5]=(_Float16)(v3.y*sc);
    pb.h[6]=(_Float16)(v3.z*sc); pb.h[7]=(_Float16)(v3.w*sc);

    int sl = r ^ L;                     // stays in 0..31 (L < 8)
    dst[L * 64 + sl]      = pa.u;       // k first-half  (slot bit5 = 0)
    dst[L * 64 + 32 + sl] = pb.u;       // k second-half (slot bit5 = 1)
}

// ---------------------------------------------------------------------------
// Main: 1024 persistent blocks. Pair p = blocks (2p, 2p+1); bs = b-half.
// Block keeps x-frags for its 512 b's in registers (wave: 4 n-tiles x 8 k =
// 128 VGPRs, loaded once from L2), then grid-strides over c-tiles p, p+512,
// ... with an explicit double-buffered pipeline: issue next tile's global
// loads -> compute current tile (8 ds_read + 32 MFMA + 64 exp per wave) ->
// transform+write other LDS buffer -> one barrier. exp-sums accumulate in
// registers across ALL tiles; single atomicAdd per b at block end.
// ---------------------------------------------------------------------------
__global__ __launch_bounds__(256, 2) void main_kernel(
    const float* __restrict__ proxies,
    const uint4* __restrict__ xfrag,
    const float* __restrict__ w, float* __restrict__ negsumR)
{
    __shared__ uint4 ldsP[2][512];      // 2 x 8 KB tile buffers

    int tid = threadIdx.x, wave = tid >> 6, lane = tid & 63;
    int bx = blockIdx.x;
    int pairId = bx >> 1;
    int bs = bx & 1;
    int L = tid & 7, r = tid >> 3;      // stage role: row r, k-segment L
    int nt0 = bs * 16 + wave * 4;       // this wave's 4 n-tiles

    // ---- prologue: issue first tile's loads, then xf loads ----
    int tile0 = pairId;
    float4 p0, p1, p2, p3;
    {
        const float4* src = (const float4*)(proxies + (size_t)(tile0 * 32 + r) * D_K + L * 16);
        p0 = src[0]; p1 = src[1]; p2 = src[2]; p3 = src[3];
    }

    uint4 xf[4][8];                     // resident x fragments (128 VGPRs)
    #pragma unroll
    for (int nt = 0; nt < 4; ++nt)
        #pragma unroll
        for (int k = 0; k < 8; ++k)
            xf[nt][k] = xfrag[((nt0 + nt) * 8 + k) * 64 + lane];

    stage_write(ldsP[0], L, r, p0, p1, p2, p3);
    __syncthreads();

    float s0 = 0.f, s1 = 0.f, s2 = 0.f, s3 = 0.f;
    int buf = 0;

    #pragma unroll 1
    for (int tile = tile0; tile < NTILE; tile += NPAIR) {
        int nxt = tile + NPAIR;
        bool have = nxt < NTILE;        // block-uniform
        if (have) {
            const float4* src = (const float4*)(proxies + (size_t)(nxt * 32 + r) * D_K + L * 16);
            p0 = src[0]; p1 = src[1]; p2 = src[2]; p3 = src[3];
        }

        uint4 a[8];
        #pragma unroll
        for (int k = 0; k < 8; ++k)
            a[k] = ldsP[buf][k * 64 + (lane ^ k)];

        #pragma unroll
        for (int h = 0; h < 2; ++h) {   // n-tile pairs (0,1) and (2,3)
            floatx16 accA, accB;
            #pragma unroll
            for (int i = 0; i < 16; ++i) { accA[i] = 0.0f; accB[i] = 0.0f; }
            #pragma unroll
            for (int k = 0; k < 8; ++k) {
                U16 ua, u0, u1;
                ua.u = a[k]; u0.u = xf[2*h][k]; u1.u = xf[2*h+1][k];
                accA = __builtin_amdgcn_mfma_f32_32x32x16_f16(ua.h, u0.h, accA, 0, 0, 0);
                accB = __builtin_amdgcn_mfma_f32_32x32x16_f16(ua.h, u1.h, accB, 0, 0, 0);
            }
            float tA0 = 0.f, tA1 = 0.f, tB0 = 0.f, tB1 = 0.f;
            #pragma unroll
            for (int i = 0; i < 16; i += 2) {
                tA0 += EXP2F(accA[i]);   tA1 += EXP2F(accA[i + 1]);
                tB0 += EXP2F(accB[i]);   tB1 += EXP2F(accB[i + 1]);
            }
            if (h == 0) { s0 += tA0 + tA1; s1 += tB0 + tB1; }
            else        { s2 += tA0 + tA1; s3 += tB0 + tB1; }
        }

        if (have) stage_write(ldsP[buf ^ 1], L, r, p0, p1, p2, p3);
        __syncthreads();
        buf ^= 1;
    }

    // ---- epilogue: one atomic per b ----
    int rep = bx & (NREP - 1);
    float* nsr = negsumR + (size_t)rep * B_N;
    float vs[4] = {s0, s1, s2, s3};
    #pragma unroll
    for (int nt = 0; nt < 4; ++nt) {
        float v = vs[nt] + __shfl_xor(vs[nt], 32, 64);   // fold c-row halves
        if (lane < 32) {
            int b = (nt0 + nt) * 32 + lane;
            atomicAdd(&nsr[b], v * w[b]);
        }
    }
}

// ---------------------------------------------------------------------------
// Finalize: loss = mean_b [ log(sum_r negsumR[r][b] - exp(-posd[b])) + posd[b] ]
// ---------------------------------------------------------------------------
__global__ __launch_bounds__(1024) void final_kernel(
    const float* __restrict__ negsumR, const float* __restrict__ posd,
    float* __restrict__ out)
{
    __shared__ float red[1024];
    int t = threadIdx.x;
    float ns = 0.0f;
    #pragma unroll 4
    for (int rr = 0; rr < NREP; ++rr) ns += negsumR[rr * B_N + t];
    float pd = posd[t];
    red[t] = logf(ns - __expf(-pd)) + pd;
    __syncthreads();
    #pragma unroll
    for (int s = 512; s > 0; s >>= 1) {
        if (t < s) red[t] += red[t + s];
        __syncthreads();
    }
    if (t == 0) out[0] = red[0] * (1.0f / 1024.0f);
}

extern "C" void kernel_launch(void* const* d_in, const int* in_sizes, int n_in,
                              void* d_out, int out_size, void* d_ws, size_t ws_size,
                              hipStream_t stream)
{
    const float* xs      = (const float*)d_in[0];
    const int*   ys      = (const int*)d_in[1];
    const float* proxies = (const float*)d_in[2];

    char* ws = (char*)d_ws;
    unsigned int* xfrag   = (unsigned int*)ws;                 // 256 KB
    float*        w       = (float*)(ws + 262144);             // 4 KB
    float*        posd    = (float*)(ws + 262144 + 4096);      // 4 KB
    float*        negsumR = (float*)(ws + 262144 + 8192);      // 256 KB (64 reps)

    prep_kernel<<<256, 256, 0, stream>>>(xs, ys, proxies, xfrag, w, posd, negsumR);
    main_kernel<<<NBLK_MAIN, 256, 0, stream>>>(proxies, (const uint4*)xfrag, w, negsumR);
    final_kernel<<<1, 1024, 0, stream>>>(negsumR, posd, (float*)d_out);
}